// Round 8
// baseline (394.907 us; speedup 1.0000x reference)
//
#include <hip/hip_runtime.h>

#define NNODES 32768
#define NEDGES 524288
#define KCL 64
#define CPG 16   // histogram chunks per graph (4096 edges each)

typedef _Float16 half8v __attribute__((ext_vector_type(8)));
typedef _Float16 half4v __attribute__((ext_vector_type(4)));
typedef float floatx4 __attribute__((ext_vector_type(4)));

__device__ __forceinline__ float wave_sum(float v) {
#pragma unroll
  for (int off = 32; off > 0; off >>= 1) v += __shfl_xor(v, off, 64);
  return v;
}

// ---------------- per-chunk LDS histograms (no global atomics) ----------------
__global__ __launch_bounds__(256) void hist2_kernel(const int* __restrict__ src, const int* __restrict__ dst,
                                                    int* __restrict__ pIn, int* __restrict__ pOut) {
  __shared__ int hIn[4096];
  __shared__ int hOut[4096];
  const int t = threadIdx.x;
  const int g = blockIdx.x >> 4;
  const int ebase = (g << 16) + ((blockIdx.x & 15) << 12);
  const int nbase = g << 12;
  for (int i = t; i < 4096; i += 256) { hIn[i] = 0; hOut[i] = 0; }
  __syncthreads();
#pragma unroll
  for (int i = 0; i < 16; ++i) {
    int e = ebase + i * 256 + t;
    atomicAdd(&hIn[dst[e] - nbase], 1);
    atomicAdd(&hOut[src[e] - nbase], 1);
  }
  __syncthreads();
  int* dIn = pIn + ((size_t)blockIdx.x << 12);
  int* dOut = pOut + ((size_t)blockIdx.x << 12);
  for (int i = t; i < 4096; i += 256) { dIn[i] = hIn[i]; dOut[i] = hOut[i]; }
}

// ---------------- per-graph scan: offs, dis, outdeg, per-chunk cursor bases ----------------
__global__ __launch_bounds__(1024) void scan2_kernel(const int* __restrict__ pIn, const int* __restrict__ pOut,
                                                     int* __restrict__ offs, int* __restrict__ cbase,
                                                     int* __restrict__ outdeg, float* __restrict__ dis) {
  __shared__ int part[1024];
  const int t = threadIdx.x;
  const int g = blockIdx.x;
  int tot[4];
  int s = 0;
#pragma unroll
  for (int j = 0; j < 4; ++j) {
    int l = t * 4 + j;
    int cnt = 0;
#pragma unroll
    for (int c = 0; c < CPG; ++c) cnt += pIn[(((size_t)(g * CPG + c)) << 12) + l];
    tot[j] = cnt;
    s += cnt;
  }
  part[t] = s;
  __syncthreads();
  for (int off = 1; off < 1024; off <<= 1) {
    int add = (t >= off) ? part[t - off] : 0;
    __syncthreads();
    part[t] += add;
    __syncthreads();
  }
  int run = (g << 16) + ((t == 0) ? 0 : part[t - 1]);
#pragma unroll
  for (int j = 0; j < 4; ++j) {
    int l = t * 4 + j;
    int n = (g << 12) + l;
    offs[n] = run;
    dis[n] = rsqrtf((float)tot[j] + 1.0f);
    int od = 0;
#pragma unroll
    for (int c = 0; c < CPG; ++c) od += pOut[(((size_t)(g * CPG + c)) << 12) + l];
    outdeg[n] = od;
    int running = run;
#pragma unroll
    for (int c = 0; c < CPG; ++c) {
      size_t idx = (((size_t)(g * CPG + c)) << 12) + l;
      cbase[idx] = running;
      running += pIn[idx];
    }
    run += tot[j];
  }
  if (g == 0 && t == 0) offs[NNODES] = NEDGES;
}

// ---------------- scatter via LDS cursors (no global atomics) ----------------
__global__ __launch_bounds__(256) void scatter2_kernel(const int* __restrict__ src, const int* __restrict__ dst,
                                                       const int* __restrict__ cbase, int* __restrict__ ssrc) {
  __shared__ int cur[4096];
  const int t = threadIdx.x;
  const int g = blockIdx.x >> 4;
  const int ebase = (g << 16) + ((blockIdx.x & 15) << 12);
  const int nbase = g << 12;
  const int* cb = cbase + ((size_t)blockIdx.x << 12);
  for (int i = t; i < 4096; i += 256) cur[i] = cb[i];
  __syncthreads();
#pragma unroll
  for (int i = 0; i < 16; ++i) {
    int e = ebase + i * 256 + t;
    int d = dst[e] - nbase;
    int pos = atomicAdd(&cur[d], 1);
    ssrc[pos] = src[e];
  }
}

// ---------------- MFMA fp16 GEMM: C[M x BN] = A[M x 128] @ W[128 x BN] ----------------
template <int BN, int ACT, int BIAS, int SCALE, int AFP32, int OUTH, int SMAX>
__global__ __launch_bounds__(256) void mgemm_kernel(const void* __restrict__ Ain, const float* __restrict__ W,
                                                    const float* __restrict__ bias, const float* __restrict__ rowscale,
                                                    const int* __restrict__ outdeg, float* __restrict__ dnp,
                                                    void* __restrict__ Cout) {
  constexpr int CT = BN / 16;
  __shared__ _Float16 WT[BN][136];
  const int t = threadIdx.x;
  for (int i = t; i < 128 * BN; i += 256) {
    int k = i / BN, n = i % BN;
    WT[n][k] = (_Float16)W[i];
  }
  __syncthreads();
  const int lane = t & 63;
  const int quad = lane >> 4, l16 = lane & 15;
  const long rowbase = (long)(blockIdx.x & 7) * 4096 + (long)(blockIdx.x >> 3) * 128 + (t >> 6) * 32;
  half8v af[2][4];
#pragma unroll
  for (int rt = 0; rt < 2; rt++)
#pragma unroll
    for (int kt = 0; kt < 4; kt++) {
      if (AFP32) {
        const float* A32 = (const float*)Ain;
        const float* p = A32 + (rowbase + rt * 16 + l16) * 128 + kt * 32 + quad * 8;
        float4 p0 = *reinterpret_cast<const float4*>(p);
        float4 p1 = *reinterpret_cast<const float4*>(p + 4);
        half8v h = {(_Float16)p0.x, (_Float16)p0.y, (_Float16)p0.z, (_Float16)p0.w,
                    (_Float16)p1.x, (_Float16)p1.y, (_Float16)p1.z, (_Float16)p1.w};
        af[rt][kt] = h;
      } else {
        const _Float16* A16 = (const _Float16*)Ain;
        af[rt][kt] = *reinterpret_cast<const half8v*>(A16 + (rowbase + rt * 16 + l16) * 128 + kt * 32 + quad * 8);
      }
    }
  floatx4 acc[2][CT];
#pragma unroll
  for (int rt = 0; rt < 2; rt++)
#pragma unroll
    for (int ct = 0; ct < CT; ct++) acc[rt][ct] = {0.f, 0.f, 0.f, 0.f};
#pragma unroll
  for (int kt = 0; kt < 4; kt++) {
    half8v bf[CT];
#pragma unroll
    for (int ct = 0; ct < CT; ct++)
      bf[ct] = *reinterpret_cast<const half8v*>(&WT[ct * 16 + l16][kt * 32 + quad * 8]);
#pragma unroll
    for (int rt = 0; rt < 2; rt++)
#pragma unroll
      for (int ct = 0; ct < CT; ct++)
        acc[rt][ct] = __builtin_amdgcn_mfma_f32_16x16x32_f16(af[rt][kt], bf[ct], acc[rt][ct], 0, 0, 0);
  }
#pragma unroll
  for (int rt = 0; rt < 2; rt++) {
#pragma unroll
    for (int r = 0; r < 4; r++) {
      long row = rowbase + rt * 16 + quad * 4 + r;
      if (SMAX) {
        float v[CT];
#pragma unroll
        for (int ct = 0; ct < CT; ct++) v[ct] = acc[rt][ct][r] + bias[ct * 16 + l16];
        float m = v[0];
#pragma unroll
        for (int ct = 1; ct < CT; ct++) m = fmaxf(m, v[ct]);
#pragma unroll
        for (int off = 1; off <= 8; off <<= 1) m = fmaxf(m, __shfl_xor(m, off, 64));
        float se = 0.f;
#pragma unroll
        for (int ct = 0; ct < CT; ct++) { v[ct] = __expf(v[ct] - m); se += v[ct]; }
#pragma unroll
        for (int off = 1; off <= 8; off <<= 1) se += __shfl_xor(se, off, 64);
        float inv = 1.0f / se;
#pragma unroll
        for (int ct = 0; ct < CT; ct++) v[ct] *= inv;
        float m2 = v[0];
#pragma unroll
        for (int ct = 1; ct < CT; ct++) m2 = fmaxf(m2, v[ct]);
#pragma unroll
        for (int off = 1; off <= 8; off <<= 1) m2 = fmaxf(m2, __shfl_xor(m2, off, 64));
        float se2 = 0.f;
#pragma unroll
        for (int ct = 0; ct < CT; ct++) { v[ct] = __expf(v[ct] - m2); se2 += v[ct]; }
#pragma unroll
        for (int off = 1; off <= 8; off <<= 1) se2 += __shfl_xor(se2, off, 64);
        float inv2 = 1.0f / se2;
        float qq = 0.f;
#pragma unroll
        for (int ct = 0; ct < CT; ct++) { v[ct] *= inv2; qq += v[ct] * v[ct]; }
#pragma unroll
        for (int off = 1; off <= 8; off <<= 1) qq += __shfl_xor(qq, off, 64);
        if (l16 == 0) dnp[row] = qq * (float)outdeg[row];
        _Float16* sh = (_Float16*)Cout;
#pragma unroll
        for (int ct = 0; ct < CT; ct++) sh[row * BN + ct * 16 + l16] = (_Float16)v[ct];
      } else {
        float sc = SCALE ? rowscale[row] : 1.f;
#pragma unroll
        for (int ct = 0; ct < CT; ct++) {
          float v = acc[rt][ct][r];
          if (SCALE) v *= sc;
          if (BIAS) v += bias[ct * 16 + l16];
          if (ACT == 1) v = fmaxf(v, 0.f);
          if (ACT == 2) v = tanhf(v);
          if (OUTH) ((_Float16*)Cout)[row * BN + ct * 16 + l16] = (_Float16)v;
          else ((float*)Cout)[row * BN + ct * 16 + l16] = v;
        }
      }
    }
  }
}

// ---------------- GCN aggregation over fp16 pre-scaled hs (XCD-swizzled, parallel tail) ----------------
__global__ __launch_bounds__(256) void aggregate_kernel(const _Float16* __restrict__ hs, const float* __restrict__ dis,
                                                        const int* __restrict__ offs, const int* __restrict__ ssrc,
                                                        const float* __restrict__ bias, _Float16* __restrict__ outh,
                                                        int relu) {
  const int lane = threadIdx.x & 63;
  const int b = blockIdx.x;
  const int node = ((b & 7) << 12) + ((b >> 3) << 2) + (threadIdx.x >> 6);
  const int q = lane >> 4;
  const int fl = (lane & 15) * 8;
  const int e0 = offs[node], e1 = offs[node + 1];
  float fa[8];
#pragma unroll
  for (int j = 0; j < 8; j++) fa[j] = 0.f;
  int e = e0;
  for (; e + 16 <= e1; e += 16) {
    int s0 = ssrc[e + q];
    int s1 = ssrc[e + 4 + q];
    int s2 = ssrc[e + 8 + q];
    int s3 = ssrc[e + 12 + q];
    half8v v0 = *reinterpret_cast<const half8v*>(hs + (size_t)s0 * 128 + fl);
    half8v v1 = *reinterpret_cast<const half8v*>(hs + (size_t)s1 * 128 + fl);
    half8v v2 = *reinterpret_cast<const half8v*>(hs + (size_t)s2 * 128 + fl);
    half8v v3 = *reinterpret_cast<const half8v*>(hs + (size_t)s3 * 128 + fl);
#pragma unroll
    for (int j = 0; j < 8; j++) fa[j] += (float)v0[j] + (float)v1[j] + (float)v2[j] + (float)v3[j];
  }
  if (e < e1) {  // parallel masked tail (<=15 edges), all loads independent
    int last = e1 - 1;
    int i0 = e + q, i1 = e + 4 + q, i2 = e + 8 + q, i3 = e + 12 + q;
    bool m0 = i0 < e1, m1 = i1 < e1, m2 = i2 < e1, m3 = i3 < e1;
    int s0 = ssrc[i0 < last ? i0 : last];
    int s1 = ssrc[i1 < last ? i1 : last];
    int s2 = ssrc[i2 < last ? i2 : last];
    int s3 = ssrc[i3 < last ? i3 : last];
    half8v v0 = *reinterpret_cast<const half8v*>(hs + (size_t)s0 * 128 + fl);
    half8v v1 = *reinterpret_cast<const half8v*>(hs + (size_t)s1 * 128 + fl);
    half8v v2 = *reinterpret_cast<const half8v*>(hs + (size_t)s2 * 128 + fl);
    half8v v3 = *reinterpret_cast<const half8v*>(hs + (size_t)s3 * 128 + fl);
#pragma unroll
    for (int j = 0; j < 8; j++) {
      fa[j] += (m0 ? (float)v0[j] : 0.f) + (m1 ? (float)v1[j] : 0.f) +
               (m2 ? (float)v2[j] : 0.f) + (m3 ? (float)v3[j] : 0.f);
    }
  }
#pragma unroll
  for (int j = 0; j < 8; j++) {
    fa[j] += __shfl_xor(fa[j], 16, 64);
    fa[j] += __shfl_xor(fa[j], 32, 64);
  }
  if (q == 0) {
    float dn = dis[node];
    half8v self = *reinterpret_cast<const half8v*>(hs + (size_t)node * 128 + fl);
    float4 b0 = *reinterpret_cast<const float4*>(bias + fl);
    float4 b1 = *reinterpret_cast<const float4*>(bias + fl + 4);
    float bb[8] = {b0.x, b0.y, b0.z, b0.w, b1.x, b1.y, b1.z, b1.w};
    half8v r;
#pragma unroll
    for (int j = 0; j < 8; j++) {
      float v = fmaf(fa[j] + (float)self[j], dn, bb[j]);
      if (relu) v = fmaxf(v, 0.f);
      r[j] = (_Float16)v;
    }
    *reinterpret_cast<half8v*>(outh + (size_t)node * 128 + fl) = r;
  }
}

// ---------------- G[m] = sum_{src->m} s_d[src]  (fp16 rows, parallel tail) ----------------
__global__ __launch_bounds__(256) void gather_kernel(const _Float16* __restrict__ sh, const int* __restrict__ offs,
                                                     const int* __restrict__ ssrc, _Float16* __restrict__ Gh) {
  const int lane = threadIdx.x & 63;
  const int b = blockIdx.x;
  const int node = ((b & 7) << 12) + ((b >> 3) << 2) + (threadIdx.x >> 6);
  const int q = lane >> 3;          // 0..7 edge slot
  const int fl = (lane & 7) * 8;    // 8 lanes x 8 halves = 64
  const int e0 = offs[node], e1 = offs[node + 1];
  float fa[8];
#pragma unroll
  for (int j = 0; j < 8; j++) fa[j] = 0.f;
  int e = e0;
  for (; e + 16 <= e1; e += 16) {
    int s0 = ssrc[e + q];
    int s1 = ssrc[e + 8 + q];
    half8v v0 = *reinterpret_cast<const half8v*>(sh + (size_t)s0 * 64 + fl);
    half8v v1 = *reinterpret_cast<const half8v*>(sh + (size_t)s1 * 64 + fl);
#pragma unroll
    for (int j = 0; j < 8; j++) fa[j] += (float)v0[j] + (float)v1[j];
  }
  if (e < e1) {
    int last = e1 - 1;
    int i0 = e + q, i1 = e + 8 + q;
    bool m0 = i0 < e1, m1 = i1 < e1;
    int s0 = ssrc[i0 < last ? i0 : last];
    int s1 = ssrc[i1 < last ? i1 : last];
    half8v v0 = *reinterpret_cast<const half8v*>(sh + (size_t)s0 * 64 + fl);
    half8v v1 = *reinterpret_cast<const half8v*>(sh + (size_t)s1 * 64 + fl);
#pragma unroll
    for (int j = 0; j < 8; j++)
      fa[j] += (m0 ? (float)v0[j] : 0.f) + (m1 ? (float)v1[j] : 0.f);
  }
#pragma unroll
  for (int j = 0; j < 8; j++) {
    fa[j] += __shfl_xor(fa[j], 8, 64);
    fa[j] += __shfl_xor(fa[j], 16, 64);
    fa[j] += __shfl_xor(fa[j], 32, 64);
  }
  if (q == 0) {
    half8v r;
#pragma unroll
    for (int j = 0; j < 8; j++) r[j] = (_Float16)fa[j];
    *reinterpret_cast<half8v*>(Gh + (size_t)node * 64 + fl) = r;
  }
}

// ---------------- fused rank reduction: C[64 x 256] = s_chunk^T [G | s | h2] ----------------
__global__ __launch_bounds__(512) void fused_atb_kernel(const _Float16* __restrict__ sh, const _Float16* __restrict__ Gh,
                                                        const _Float16* __restrict__ h2, float* __restrict__ pF) {
  __shared__ float Xs[32][64];
  __shared__ float Ys[32][256];
  const int t = threadIdx.x;
  const int g = blockIdx.x & 7, chunk = blockIdx.x >> 3;
  const int n0 = g * 4096 + chunk * 128;
  const int rg = t >> 6;
  const int cl = t & 63;
  float acc[8][4];
#pragma unroll
  for (int r = 0; r < 8; r++)
#pragma unroll
    for (int j = 0; j < 4; j++) acc[r][j] = 0.f;

  for (int kt = 0; kt < 4; ++kt) {
    const int nb = n0 + kt * 32;
    {
      int k = t >> 4, c = (t & 15) * 4;
      half4v hv = *reinterpret_cast<const half4v*>(&sh[(size_t)(nb + k) * 64 + c]);
      float4 val = {(float)hv[0], (float)hv[1], (float)hv[2], (float)hv[3]};
      *reinterpret_cast<float4*>(&Xs[k][c]) = val;
    }
#pragma unroll
    for (int it = 0; it < 4; ++it) {
      int slot = it * 512 + t;
      int k = slot >> 6, c = (slot & 63) * 4;
      half4v hv;
      if (c < 64)       hv = *reinterpret_cast<const half4v*>(&Gh[(size_t)(nb + k) * 64 + c]);
      else if (c < 128) hv = *reinterpret_cast<const half4v*>(&sh[(size_t)(nb + k) * 64 + (c - 64)]);
      else              hv = *reinterpret_cast<const half4v*>(&h2[(size_t)(nb + k) * 128 + (c - 128)]);
      float4 val = {(float)hv[0], (float)hv[1], (float)hv[2], (float)hv[3]};
      *reinterpret_cast<float4*>(&Ys[k][c]) = val;
    }
    __syncthreads();
#pragma unroll
    for (int k = 0; k < 32; ++k) {
      float4 b4 = *reinterpret_cast<const float4*>(&Ys[k][cl * 4]);
      float4 a0 = *reinterpret_cast<const float4*>(&Xs[k][rg * 8]);
      float4 a1 = *reinterpret_cast<const float4*>(&Xs[k][rg * 8 + 4]);
      float a[8] = {a0.x, a0.y, a0.z, a0.w, a1.x, a1.y, a1.z, a1.w};
#pragma unroll
      for (int r = 0; r < 8; r++) {
        acc[r][0] = fmaf(a[r], b4.x, acc[r][0]);
        acc[r][1] = fmaf(a[r], b4.y, acc[r][1]);
        acc[r][2] = fmaf(a[r], b4.z, acc[r][2]);
        acc[r][3] = fmaf(a[r], b4.w, acc[r][3]);
      }
    }
    __syncthreads();
  }
  float* dst = pF + (size_t)blockIdx.x * 16384;
#pragma unroll
  for (int r = 0; r < 8; r++) {
    float4 o4 = {acc[r][0], acc[r][1], acc[r][2], acc[r][3]};
    *reinterpret_cast<float4*>(&dst[(rg * 8 + r) * 256 + cl * 4]) = o4;
  }
}

// ---------------- finale: merge partials + losses + adj-norm + pooled MFMA GEMM ----------------
// One block per graph (8 blocks, 256 threads).
__global__ __launch_bounds__(256) void finale_kernel(const float* __restrict__ pF, const float* __restrict__ Wo,
                                                     const float* __restrict__ bo, const float* __restrict__ dn,
                                                     float* __restrict__ out) {
  __shared__ _Float16 outpS[64][136];
  __shared__ _Float16 WoT[128][136];
  __shared__ float red[256];
  __shared__ float rowsum[64];
  __shared__ float dw[4], w1[4], w2[4], w3[4];
  const int g = blockIdx.x, t = threadIdx.x;

  // stage Wo^T (fp32 [128k][128n] -> WoT[n][k] fp16)
#pragma unroll
  for (int i = 0; i < 16; i++) {
    int idx = i * 256 + t;
    int k = idx >> 5, n4 = (idx & 31) * 4;
    float4 w = *reinterpret_cast<const float4*>(Wo + k * 128 + n4);
    WoT[n4 + 0][k] = (_Float16)w.x;
    WoT[n4 + 1][k] = (_Float16)w.y;
    WoT[n4 + 2][k] = (_Float16)w.z;
    WoT[n4 + 3][k] = (_Float16)w.w;
  }

  const int row = t >> 2, p = t & 3;
  // merge A (out_adj) into registers: 16 cols j = p*16..p*16+15
  float Areg[16];
#pragma unroll
  for (int c4 = 0; c4 < 4; c4++) {
    int o4 = row * 64 + p * 4 + c4;
    float sx = 0.f, sy = 0.f, sz = 0.f, sw = 0.f;
#pragma unroll
    for (int q = 0; q < 32; q++) {
      float4 v = *reinterpret_cast<const float4*>(pF + (size_t)(q * 8 + g) * 16384 + o4 * 4);
      sx += v.x; sy += v.y; sz += v.z; sw += v.w;
    }
    Areg[c4 * 4 + 0] = sx; Areg[c4 * 4 + 1] = sy; Areg[c4 * 4 + 2] = sz; Areg[c4 * 4 + 3] = sw;
  }
  // merge S (ss) inline into trs/ssq partials
  float trs_p = 0.f, ssq_p = 0.f;
#pragma unroll
  for (int c4 = 0; c4 < 4; c4++) {
    int o4 = row * 64 + 16 + p * 4 + c4;
    float sx = 0.f, sy = 0.f, sz = 0.f, sw = 0.f;
#pragma unroll
    for (int q = 0; q < 32; q++) {
      float4 v = *reinterpret_cast<const float4*>(pF + (size_t)(q * 8 + g) * 16384 + o4 * 4);
      sx += v.x; sy += v.y; sz += v.z; sw += v.w;
    }
    float vv[4] = {sx, sy, sz, sw};
#pragma unroll
    for (int jj = 0; jj < 4; jj++) {
      ssq_p += vv[jj] * vv[jj];
      int col = p * 16 + c4 * 4 + jj;
      if (col == row) trs_p += vv[jj];
    }
  }
  // merge outp -> outpS (fp16)
#pragma unroll
  for (int i = 0; i < 8; i++) {
    int idx = i * 256 + t;               // 2048 float4 slots
    int orow = idx >> 5, k4 = idx & 31;
    int o4 = orow * 64 + 32 + k4;
    float sx = 0.f, sy = 0.f, sz = 0.f, sw = 0.f;
#pragma unroll
    for (int q = 0; q < 32; q++) {
      float4 v = *reinterpret_cast<const float4*>(pF + (size_t)(q * 8 + g) * 16384 + o4 * 4);
      sx += v.x; sy += v.y; sz += v.z; sw += v.w;
    }
    outpS[orow][k4 * 4 + 0] = (_Float16)sx;
    outpS[orow][k4 * 4 + 1] = (_Float16)sy;
    outpS[orow][k4 * 4 + 2] = (_Float16)sz;
    outpS[orow][k4 * 4 + 3] = (_Float16)sw;
  }
  // mincut den
  float da = 0.f;
#pragma unroll
  for (int i = 0; i < 16; i++) da += dn[g * 4096 + i * 256 + t];
  float dws = wave_sum(da);
  if ((t & 63) == 0) dw[t >> 6] = dws;

  // row sums (off-diag) + traces
  float rs = 0.f, tra = 0.f;
#pragma unroll
  for (int c = 0; c < 16; c++) {
    int j = p * 16 + c;
    if (j == row) tra += Areg[c];
    else rs += Areg[c];
  }
  red[t] = rs;
  __syncthreads();
  if (p == 0) rowsum[row] = red[t] + red[t + 1] + red[t + 2] + red[t + 3];
  float v1 = wave_sum(tra), v2 = wave_sum(trs_p), v3 = wave_sum(ssq_p);
  if ((t & 63) == 0) { int w = t >> 6; w1[w] = v1; w2[w] = v2; w3[w] = v3; }
  __syncthreads();
  if (t == 0) {
    float TRA = w1[0] + w1[1] + w1[2] + w1[3];
    float TRS = w2[0] + w2[1] + w2[2] + w2[3];
    float SSQ = w3[0] + w3[1] + w3[2] + w3[3];
    float DEN = dw[0] + dw[1] + dw[2] + dw[3];
    atomicAdd(&out[98816], -(TRA / DEN) * 0.125f);
    float ssn = sqrtf(SSQ);
    atomicAdd(&out[98817], sqrtf(2.0f - TRS / (4.0f * ssn)) * 0.125f);
  }
  float di = sqrtf(rowsum[row]) + 1e-15f;
#pragma unroll
  for (int c = 0; c < 16; c++) {
    int j = p * 16 + c;
    float v = (j == row) ? 0.f : Areg[c];
    float dj = sqrtf(rowsum[j]) + 1e-15f;
    out[65536 + g * 4096 + row * 64 + j] = v / (di * dj);
  }
  if (t < 64) out[98304 + g * 64 + t] = (float)g;

  // pooled_x = relu(outp @ Wo + bo) via MFMA: M=64 (4 waves x 16 rows), N=128, K=128
  const int lane = t & 63;
  const int quad = lane >> 4, l16 = lane & 15;
  const int w = t >> 6;
  floatx4 acc[8];
#pragma unroll
  for (int ct = 0; ct < 8; ct++) acc[ct] = {0.f, 0.f, 0.f, 0.f};
#pragma unroll
  for (int kt = 0; kt < 4; kt++) {
    half8v af = *reinterpret_cast<const half8v*>(&outpS[w * 16 + l16][kt * 32 + quad * 8]);
#pragma unroll
    for (int ct = 0; ct < 8; ct++) {
      half8v bf = *reinterpret_cast<const half8v*>(&WoT[ct * 16 + l16][kt * 32 + quad * 8]);
      acc[ct] = __builtin_amdgcn_mfma_f32_16x16x32_f16(af, bf, acc[ct], 0, 0, 0);
    }
  }
#pragma unroll
  for (int r = 0; r < 4; r++) {
    int orow = w * 16 + quad * 4 + r;
#pragma unroll
    for (int ct = 0; ct < 8; ct++) {
      int col = ct * 16 + l16;
      float v = fmaxf(acc[ct][r] + bo[col], 0.f);
      out[(g * 64 + orow) * 128 + col] = v;
    }
  }
}

extern "C" void kernel_launch(void* const* d_in, const int* in_sizes, int n_in,
                              void* d_out, int out_size, void* d_ws, size_t ws_size,
                              hipStream_t stream) {
  const float* x   = (const float*)d_in[0];
  const int*   ei  = (const int*)d_in[1];
  const float* W1  = (const float*)d_in[3];
  const float* b1  = (const float*)d_in[4];
  const float* W2  = (const float*)d_in[5];
  const float* b2  = (const float*)d_in[6];
  const float* Wa1 = (const float*)d_in[7];
  const float* ba1 = (const float*)d_in[8];
  const float* Wa2 = (const float*)d_in[9];
  const float* ba2 = (const float*)d_in[10];
  const float* Wo  = (const float*)d_in[11];
  const float* bo  = (const float*)d_in[12];
  const int* src = ei;
  const int* dst = ei + NEDGES;
  float* out = (float*)d_out;

  char* ws = (char*)d_ws;
  size_t o = 0;
  auto alloc = [&](size_t bytes) -> void* {
    void* p = ws + o;
    o += (bytes + 255) & ~(size_t)255;
    return p;
  };
  _Float16* h16A = (_Float16*)alloc((size_t)NNODES * 128 * 2);  // 8 MB
  _Float16* h16B = (_Float16*)alloc((size_t)NNODES * 128 * 2);  // 8 MB
  _Float16* h16C = (_Float16*)alloc((size_t)NNODES * 128 * 2);  // 8 MB (h2, persists)
  _Float16* sh   = (_Float16*)alloc((size_t)NNODES * 64 * 2);   // 4 MB (s_d fp16)
  _Float16* Gh   = (_Float16*)alloc((size_t)NNODES * 64 * 2);   // 4 MB
  float* pF    = (float*)alloc((size_t)256 * 16384 * 4);        // 16 MB
  float* dis   = (float*)alloc((size_t)NNODES * 4);
  int* outdeg  = (int*)alloc((size_t)NNODES * 4);
  int* offs    = (int*)alloc((size_t)(NNODES + 1) * 4);
  int* ssrc    = (int*)alloc((size_t)NEDGES * 4);
  int* pIn     = (int*)alloc((size_t)8 * CPG * 4096 * 4);
  int* pOut    = (int*)alloc((size_t)8 * CPG * 4096 * 4);
  int* cbase   = (int*)alloc((size_t)8 * CPG * 4096 * 4);
  float* dn    = (float*)alloc((size_t)NNODES * 4);

  hipMemsetAsync(out + 98816, 0, 2 * sizeof(float), stream);

  hist2_kernel<<<8 * CPG, 256, 0, stream>>>(src, dst, pIn, pOut);
  scan2_kernel<<<8, 1024, 0, stream>>>(pIn, pOut, offs, cbase, outdeg, dis);
  scatter2_kernel<<<8 * CPG, 256, 0, stream>>>(src, dst, cbase, ssrc);

  // GCN layer 1: hs = dis .* (x @ W1) [fp32 in, fp16 out]; h1 = relu(...)
  mgemm_kernel<128, 0, 0, 1, 1, 1, 0><<<NNODES / 128, 256, 0, stream>>>(x, W1, nullptr, dis, nullptr, nullptr, h16A);
  aggregate_kernel<<<NNODES / 4, 256, 0, stream>>>(h16A, dis, offs, ssrc, b1, h16B, 1);
  // GCN layer 2: h2 [fp16]
  mgemm_kernel<128, 0, 0, 1, 0, 1, 0><<<NNODES / 128, 256, 0, stream>>>(h16B, W2, nullptr, dis, nullptr, nullptr, h16A);
  aggregate_kernel<<<NNODES / 4, 256, 0, stream>>>(h16A, dis, offs, ssrc, b2, h16C, 0);

  // assignment MLP: z = tanh(h2 @ Wa1 + ba1) [fp16]; s_d = dsoftmax(z @ Wa2 + ba2) [fp16, fused]
  mgemm_kernel<128, 2, 1, 0, 0, 1, 0><<<NNODES / 128, 256, 0, stream>>>(h16C, Wa1, ba1, nullptr, nullptr, nullptr, h16A);
  mgemm_kernel<64, 0, 1, 0, 0, 0, 1><<<NNODES / 128, 256, 0, stream>>>(h16A, Wa2, ba2, nullptr, outdeg, dn, sh);

  gather_kernel<<<NNODES / 4, 256, 0, stream>>>(sh, offs, ssrc, Gh);
  fused_atb_kernel<<<256, 512, 0, stream>>>(sh, Gh, h16C, pF);
  finale_kernel<<<8, 256, 0, stream>>>(pF, Wo, bo, dn, out);
}

// Round 9
// 241.230 us; speedup vs baseline: 1.6371x; 1.6371x over previous
//
#include <hip/hip_runtime.h>

#define NNODES 32768
#define NEDGES 524288
#define KCL 64
#define CPG 16   // histogram chunks per graph (4096 edges each)

typedef _Float16 half8v __attribute__((ext_vector_type(8)));
typedef _Float16 half4v __attribute__((ext_vector_type(4)));
typedef float floatx4 __attribute__((ext_vector_type(4)));

__device__ __forceinline__ float wave_sum(float v) {
#pragma unroll
  for (int off = 32; off > 0; off >>= 1) v += __shfl_xor(v, off, 64);
  return v;
}

// ---------------- per-chunk LDS histograms (no global atomics) ----------------
__global__ __launch_bounds__(256) void hist2_kernel(const int* __restrict__ src, const int* __restrict__ dst,
                                                    int* __restrict__ pIn, int* __restrict__ pOut) {
  __shared__ int hIn[4096];
  __shared__ int hOut[4096];
  const int t = threadIdx.x;
  const int g = blockIdx.x >> 4;
  const int ebase = (g << 16) + ((blockIdx.x & 15) << 12);
  const int nbase = g << 12;
  for (int i = t; i < 4096; i += 256) { hIn[i] = 0; hOut[i] = 0; }
  __syncthreads();
#pragma unroll
  for (int i = 0; i < 16; ++i) {
    int e = ebase + i * 256 + t;
    atomicAdd(&hIn[dst[e] - nbase], 1);
    atomicAdd(&hOut[src[e] - nbase], 1);
  }
  __syncthreads();
  int* dIn = pIn + ((size_t)blockIdx.x << 12);
  int* dOut = pOut + ((size_t)blockIdx.x << 12);
  for (int i = t; i < 4096; i += 256) { dIn[i] = hIn[i]; dOut[i] = hOut[i]; }
}

// ---------------- per-graph scan: offs, dis, outdeg, per-chunk cursor bases ----------------
__global__ __launch_bounds__(1024) void scan2_kernel(const int* __restrict__ pIn, const int* __restrict__ pOut,
                                                     int* __restrict__ offs, int* __restrict__ cbase,
                                                     int* __restrict__ outdeg, float* __restrict__ dis) {
  __shared__ int part[1024];
  const int t = threadIdx.x;
  const int g = blockIdx.x;
  int tot[4];
  int s = 0;
#pragma unroll
  for (int j = 0; j < 4; ++j) {
    int l = t * 4 + j;
    int cnt = 0;
#pragma unroll
    for (int c = 0; c < CPG; ++c) cnt += pIn[(((size_t)(g * CPG + c)) << 12) + l];
    tot[j] = cnt;
    s += cnt;
  }
  part[t] = s;
  __syncthreads();
  for (int off = 1; off < 1024; off <<= 1) {
    int add = (t >= off) ? part[t - off] : 0;
    __syncthreads();
    part[t] += add;
    __syncthreads();
  }
  int run = (g << 16) + ((t == 0) ? 0 : part[t - 1]);
#pragma unroll
  for (int j = 0; j < 4; ++j) {
    int l = t * 4 + j;
    int n = (g << 12) + l;
    offs[n] = run;
    dis[n] = rsqrtf((float)tot[j] + 1.0f);
    int od = 0;
#pragma unroll
    for (int c = 0; c < CPG; ++c) od += pOut[(((size_t)(g * CPG + c)) << 12) + l];
    outdeg[n] = od;
    int running = run;
#pragma unroll
    for (int c = 0; c < CPG; ++c) {
      size_t idx = (((size_t)(g * CPG + c)) << 12) + l;
      cbase[idx] = running;
      running += pIn[idx];
    }
    run += tot[j];
  }
  if (g == 0 && t == 0) offs[NNODES] = NEDGES;
}

// ---------------- scatter via LDS cursors (no global atomics) ----------------
__global__ __launch_bounds__(256) void scatter2_kernel(const int* __restrict__ src, const int* __restrict__ dst,
                                                       const int* __restrict__ cbase, int* __restrict__ ssrc) {
  __shared__ int cur[4096];
  const int t = threadIdx.x;
  const int g = blockIdx.x >> 4;
  const int ebase = (g << 16) + ((blockIdx.x & 15) << 12);
  const int nbase = g << 12;
  const int* cb = cbase + ((size_t)blockIdx.x << 12);
  for (int i = t; i < 4096; i += 256) cur[i] = cb[i];
  __syncthreads();
#pragma unroll
  for (int i = 0; i < 16; ++i) {
    int e = ebase + i * 256 + t;
    int d = dst[e] - nbase;
    int pos = atomicAdd(&cur[d], 1);
    ssrc[pos] = src[e];
  }
}

// ---------------- MFMA fp16 GEMM: C[M x BN] = A[M x 128] @ W[128 x BN] ----------------
template <int BN, int ACT, int BIAS, int SCALE, int AFP32, int OUTH, int SMAX>
__global__ __launch_bounds__(256) void mgemm_kernel(const void* __restrict__ Ain, const float* __restrict__ W,
                                                    const float* __restrict__ bias, const float* __restrict__ rowscale,
                                                    const int* __restrict__ outdeg, float* __restrict__ dnp,
                                                    void* __restrict__ Cout) {
  constexpr int CT = BN / 16;
  __shared__ _Float16 WT[BN][136];
  const int t = threadIdx.x;
  for (int i = t; i < 128 * BN; i += 256) {
    int k = i / BN, n = i % BN;
    WT[n][k] = (_Float16)W[i];
  }
  __syncthreads();
  const int lane = t & 63;
  const int quad = lane >> 4, l16 = lane & 15;
  const long rowbase = (long)(blockIdx.x & 7) * 4096 + (long)(blockIdx.x >> 3) * 128 + (t >> 6) * 32;
  half8v af[2][4];
#pragma unroll
  for (int rt = 0; rt < 2; rt++)
#pragma unroll
    for (int kt = 0; kt < 4; kt++) {
      if (AFP32) {
        const float* A32 = (const float*)Ain;
        const float* p = A32 + (rowbase + rt * 16 + l16) * 128 + kt * 32 + quad * 8;
        float4 p0 = *reinterpret_cast<const float4*>(p);
        float4 p1 = *reinterpret_cast<const float4*>(p + 4);
        half8v h = {(_Float16)p0.x, (_Float16)p0.y, (_Float16)p0.z, (_Float16)p0.w,
                    (_Float16)p1.x, (_Float16)p1.y, (_Float16)p1.z, (_Float16)p1.w};
        af[rt][kt] = h;
      } else {
        const _Float16* A16 = (const _Float16*)Ain;
        af[rt][kt] = *reinterpret_cast<const half8v*>(A16 + (rowbase + rt * 16 + l16) * 128 + kt * 32 + quad * 8);
      }
    }
  floatx4 acc[2][CT];
#pragma unroll
  for (int rt = 0; rt < 2; rt++)
#pragma unroll
    for (int ct = 0; ct < CT; ct++) acc[rt][ct] = {0.f, 0.f, 0.f, 0.f};
#pragma unroll
  for (int kt = 0; kt < 4; kt++) {
    half8v bf[CT];
#pragma unroll
    for (int ct = 0; ct < CT; ct++)
      bf[ct] = *reinterpret_cast<const half8v*>(&WT[ct * 16 + l16][kt * 32 + quad * 8]);
#pragma unroll
    for (int rt = 0; rt < 2; rt++)
#pragma unroll
      for (int ct = 0; ct < CT; ct++)
        acc[rt][ct] = __builtin_amdgcn_mfma_f32_16x16x32_f16(af[rt][kt], bf[ct], acc[rt][ct], 0, 0, 0);
  }
#pragma unroll
  for (int rt = 0; rt < 2; rt++) {
#pragma unroll
    for (int r = 0; r < 4; r++) {
      long row = rowbase + rt * 16 + quad * 4 + r;
      if (SMAX) {
        float v[CT];
#pragma unroll
        for (int ct = 0; ct < CT; ct++) v[ct] = acc[rt][ct][r] + bias[ct * 16 + l16];
        float m = v[0];
#pragma unroll
        for (int ct = 1; ct < CT; ct++) m = fmaxf(m, v[ct]);
#pragma unroll
        for (int off = 1; off <= 8; off <<= 1) m = fmaxf(m, __shfl_xor(m, off, 64));
        float se = 0.f;
#pragma unroll
        for (int ct = 0; ct < CT; ct++) { v[ct] = __expf(v[ct] - m); se += v[ct]; }
#pragma unroll
        for (int off = 1; off <= 8; off <<= 1) se += __shfl_xor(se, off, 64);
        float inv = 1.0f / se;
#pragma unroll
        for (int ct = 0; ct < CT; ct++) v[ct] *= inv;
        float m2 = v[0];
#pragma unroll
        for (int ct = 1; ct < CT; ct++) m2 = fmaxf(m2, v[ct]);
#pragma unroll
        for (int off = 1; off <= 8; off <<= 1) m2 = fmaxf(m2, __shfl_xor(m2, off, 64));
        float se2 = 0.f;
#pragma unroll
        for (int ct = 0; ct < CT; ct++) { v[ct] = __expf(v[ct] - m2); se2 += v[ct]; }
#pragma unroll
        for (int off = 1; off <= 8; off <<= 1) se2 += __shfl_xor(se2, off, 64);
        float inv2 = 1.0f / se2;
        float qq = 0.f;
#pragma unroll
        for (int ct = 0; ct < CT; ct++) { v[ct] *= inv2; qq += v[ct] * v[ct]; }
#pragma unroll
        for (int off = 1; off <= 8; off <<= 1) qq += __shfl_xor(qq, off, 64);
        if (l16 == 0) dnp[row] = qq * (float)outdeg[row];
        _Float16* sh = (_Float16*)Cout;
#pragma unroll
        for (int ct = 0; ct < CT; ct++) sh[row * BN + ct * 16 + l16] = (_Float16)v[ct];
      } else {
        float sc = SCALE ? rowscale[row] : 1.f;
#pragma unroll
        for (int ct = 0; ct < CT; ct++) {
          float v = acc[rt][ct][r];
          if (SCALE) v *= sc;
          if (BIAS) v += bias[ct * 16 + l16];
          if (ACT == 1) v = fmaxf(v, 0.f);
          if (ACT == 2) v = tanhf(v);
          if (OUTH) ((_Float16*)Cout)[row * BN + ct * 16 + l16] = (_Float16)v;
          else ((float*)Cout)[row * BN + ct * 16 + l16] = v;
        }
      }
    }
  }
}

// ---------------- GCN aggregation over fp16 pre-scaled hs (XCD-swizzled, parallel tail) ----------------
__global__ __launch_bounds__(256) void aggregate_kernel(const _Float16* __restrict__ hs, const float* __restrict__ dis,
                                                        const int* __restrict__ offs, const int* __restrict__ ssrc,
                                                        const float* __restrict__ bias, _Float16* __restrict__ outh,
                                                        int relu) {
  const int lane = threadIdx.x & 63;
  const int b = blockIdx.x;
  const int node = ((b & 7) << 12) + ((b >> 3) << 2) + (threadIdx.x >> 6);
  const int q = lane >> 4;
  const int fl = (lane & 15) * 8;
  const int e0 = offs[node], e1 = offs[node + 1];
  float fa[8];
#pragma unroll
  for (int j = 0; j < 8; j++) fa[j] = 0.f;
  int e = e0;
  for (; e + 16 <= e1; e += 16) {
    int s0 = ssrc[e + q];
    int s1 = ssrc[e + 4 + q];
    int s2 = ssrc[e + 8 + q];
    int s3 = ssrc[e + 12 + q];
    half8v v0 = *reinterpret_cast<const half8v*>(hs + (size_t)s0 * 128 + fl);
    half8v v1 = *reinterpret_cast<const half8v*>(hs + (size_t)s1 * 128 + fl);
    half8v v2 = *reinterpret_cast<const half8v*>(hs + (size_t)s2 * 128 + fl);
    half8v v3 = *reinterpret_cast<const half8v*>(hs + (size_t)s3 * 128 + fl);
#pragma unroll
    for (int j = 0; j < 8; j++) fa[j] += (float)v0[j] + (float)v1[j] + (float)v2[j] + (float)v3[j];
  }
  if (e < e1) {  // parallel masked tail (<=15 edges), all loads independent
    int last = e1 - 1;
    int i0 = e + q, i1 = e + 4 + q, i2 = e + 8 + q, i3 = e + 12 + q;
    bool m0 = i0 < e1, m1 = i1 < e1, m2 = i2 < e1, m3 = i3 < e1;
    int s0 = ssrc[i0 < last ? i0 : last];
    int s1 = ssrc[i1 < last ? i1 : last];
    int s2 = ssrc[i2 < last ? i2 : last];
    int s3 = ssrc[i3 < last ? i3 : last];
    half8v v0 = *reinterpret_cast<const half8v*>(hs + (size_t)s0 * 128 + fl);
    half8v v1 = *reinterpret_cast<const half8v*>(hs + (size_t)s1 * 128 + fl);
    half8v v2 = *reinterpret_cast<const half8v*>(hs + (size_t)s2 * 128 + fl);
    half8v v3 = *reinterpret_cast<const half8v*>(hs + (size_t)s3 * 128 + fl);
#pragma unroll
    for (int j = 0; j < 8; j++) {
      fa[j] += (m0 ? (float)v0[j] : 0.f) + (m1 ? (float)v1[j] : 0.f) +
               (m2 ? (float)v2[j] : 0.f) + (m3 ? (float)v3[j] : 0.f);
    }
  }
#pragma unroll
  for (int j = 0; j < 8; j++) {
    fa[j] += __shfl_xor(fa[j], 16, 64);
    fa[j] += __shfl_xor(fa[j], 32, 64);
  }
  if (q == 0) {
    float dn = dis[node];
    half8v self = *reinterpret_cast<const half8v*>(hs + (size_t)node * 128 + fl);
    float4 b0 = *reinterpret_cast<const float4*>(bias + fl);
    float4 b1 = *reinterpret_cast<const float4*>(bias + fl + 4);
    float bb[8] = {b0.x, b0.y, b0.z, b0.w, b1.x, b1.y, b1.z, b1.w};
    half8v r;
#pragma unroll
    for (int j = 0; j < 8; j++) {
      float v = fmaf(fa[j] + (float)self[j], dn, bb[j]);
      if (relu) v = fmaxf(v, 0.f);
      r[j] = (_Float16)v;
    }
    *reinterpret_cast<half8v*>(outh + (size_t)node * 128 + fl) = r;
  }
}

// ---------------- G[m] = sum_{src->m} s_d[src]  (fp16 rows, parallel tail) ----------------
__global__ __launch_bounds__(256) void gather_kernel(const _Float16* __restrict__ sh, const int* __restrict__ offs,
                                                     const int* __restrict__ ssrc, _Float16* __restrict__ Gh) {
  const int lane = threadIdx.x & 63;
  const int b = blockIdx.x;
  const int node = ((b & 7) << 12) + ((b >> 3) << 2) + (threadIdx.x >> 6);
  const int q = lane >> 3;          // 0..7 edge slot
  const int fl = (lane & 7) * 8;    // 8 lanes x 8 halves = 64
  const int e0 = offs[node], e1 = offs[node + 1];
  float fa[8];
#pragma unroll
  for (int j = 0; j < 8; j++) fa[j] = 0.f;
  int e = e0;
  for (; e + 16 <= e1; e += 16) {
    int s0 = ssrc[e + q];
    int s1 = ssrc[e + 8 + q];
    half8v v0 = *reinterpret_cast<const half8v*>(sh + (size_t)s0 * 64 + fl);
    half8v v1 = *reinterpret_cast<const half8v*>(sh + (size_t)s1 * 64 + fl);
#pragma unroll
    for (int j = 0; j < 8; j++) fa[j] += (float)v0[j] + (float)v1[j];
  }
  if (e < e1) {
    int last = e1 - 1;
    int i0 = e + q, i1 = e + 8 + q;
    bool m0 = i0 < e1, m1 = i1 < e1;
    int s0 = ssrc[i0 < last ? i0 : last];
    int s1 = ssrc[i1 < last ? i1 : last];
    half8v v0 = *reinterpret_cast<const half8v*>(sh + (size_t)s0 * 64 + fl);
    half8v v1 = *reinterpret_cast<const half8v*>(sh + (size_t)s1 * 64 + fl);
#pragma unroll
    for (int j = 0; j < 8; j++)
      fa[j] += (m0 ? (float)v0[j] : 0.f) + (m1 ? (float)v1[j] : 0.f);
  }
#pragma unroll
  for (int j = 0; j < 8; j++) {
    fa[j] += __shfl_xor(fa[j], 8, 64);
    fa[j] += __shfl_xor(fa[j], 16, 64);
    fa[j] += __shfl_xor(fa[j], 32, 64);
  }
  if (q == 0) {
    half8v r;
#pragma unroll
    for (int j = 0; j < 8; j++) r[j] = (_Float16)fa[j];
    *reinterpret_cast<half8v*>(Gh + (size_t)node * 64 + fl) = r;
  }
}

// ---------------- fused rank reduction: C[64 x 256] = s_chunk^T [G | s | h2] ----------------
__global__ __launch_bounds__(512) void fused_atb_kernel(const _Float16* __restrict__ sh, const _Float16* __restrict__ Gh,
                                                        const _Float16* __restrict__ h2, float* __restrict__ pF) {
  __shared__ float Xs[32][64];
  __shared__ float Ys[32][256];
  const int t = threadIdx.x;
  const int g = blockIdx.x & 7, chunk = blockIdx.x >> 3;
  const int n0 = g * 4096 + chunk * 128;
  const int rg = t >> 6;
  const int cl = t & 63;
  float acc[8][4];
#pragma unroll
  for (int r = 0; r < 8; r++)
#pragma unroll
    for (int j = 0; j < 4; j++) acc[r][j] = 0.f;

  for (int kt = 0; kt < 4; ++kt) {
    const int nb = n0 + kt * 32;
    {
      int k = t >> 4, c = (t & 15) * 4;
      half4v hv = *reinterpret_cast<const half4v*>(&sh[(size_t)(nb + k) * 64 + c]);
      float4 val = {(float)hv[0], (float)hv[1], (float)hv[2], (float)hv[3]};
      *reinterpret_cast<float4*>(&Xs[k][c]) = val;
    }
#pragma unroll
    for (int it = 0; it < 4; ++it) {
      int slot = it * 512 + t;
      int k = slot >> 6, c = (slot & 63) * 4;
      half4v hv;
      if (c < 64)       hv = *reinterpret_cast<const half4v*>(&Gh[(size_t)(nb + k) * 64 + c]);
      else if (c < 128) hv = *reinterpret_cast<const half4v*>(&sh[(size_t)(nb + k) * 64 + (c - 64)]);
      else              hv = *reinterpret_cast<const half4v*>(&h2[(size_t)(nb + k) * 128 + (c - 128)]);
      float4 val = {(float)hv[0], (float)hv[1], (float)hv[2], (float)hv[3]};
      *reinterpret_cast<float4*>(&Ys[k][c]) = val;
    }
    __syncthreads();
#pragma unroll
    for (int k = 0; k < 32; ++k) {
      float4 b4 = *reinterpret_cast<const float4*>(&Ys[k][cl * 4]);
      float4 a0 = *reinterpret_cast<const float4*>(&Xs[k][rg * 8]);
      float4 a1 = *reinterpret_cast<const float4*>(&Xs[k][rg * 8 + 4]);
      float a[8] = {a0.x, a0.y, a0.z, a0.w, a1.x, a1.y, a1.z, a1.w};
#pragma unroll
      for (int r = 0; r < 8; r++) {
        acc[r][0] = fmaf(a[r], b4.x, acc[r][0]);
        acc[r][1] = fmaf(a[r], b4.y, acc[r][1]);
        acc[r][2] = fmaf(a[r], b4.z, acc[r][2]);
        acc[r][3] = fmaf(a[r], b4.w, acc[r][3]);
      }
    }
    __syncthreads();
  }
  float* dst = pF + (size_t)blockIdx.x * 16384;
#pragma unroll
  for (int r = 0; r < 8; r++) {
    float4 o4 = {acc[r][0], acc[r][1], acc[r][2], acc[r][3]};
    *reinterpret_cast<float4*>(&dst[(rg * 8 + r) * 256 + cl * 4]) = o4;
  }
}

// ---------------- merge 32 partials/graph -> oadj (fp32), ssb (fp32), outp (fp16) ----------------
__global__ __launch_bounds__(256) void merge_kernel(const float* __restrict__ pF, float* __restrict__ oadj,
                                                    float* __restrict__ ssb, _Float16* __restrict__ outp16) {
  int idx = blockIdx.x * 256 + threadIdx.x;
  int g = idx >> 12, o4 = idx & 4095;
  float sx = 0.f, sy = 0.f, sz = 0.f, sw = 0.f;
#pragma unroll
  for (int q = 0; q < 32; ++q) {
    float4 v = *reinterpret_cast<const float4*>(pF + (size_t)(q * 8 + g) * 16384 + o4 * 4);
    sx += v.x; sy += v.y; sz += v.z; sw += v.w;
  }
  int row = o4 >> 6;
  int c = (o4 & 63) * 4;
  if (c < 64) {
    float4 o = {sx, sy, sz, sw};
    *reinterpret_cast<float4*>(&oadj[g * 4096 + row * 64 + c]) = o;
  } else if (c < 128) {
    float4 o = {sx, sy, sz, sw};
    *reinterpret_cast<float4*>(&ssb[g * 4096 + row * 64 + (c - 64)]) = o;
  } else {
    half4v h = {(_Float16)sx, (_Float16)sy, (_Float16)sz, (_Float16)sw};
    *reinterpret_cast<half4v*>(&outp16[g * 8192 + row * 128 + (c - 128)]) = h;
  }
}

// ---------------- epilogue2: losses + adj-norm + pooled MFMA GEMM (8 blocks) ----------------
__global__ __launch_bounds__(256) void epilogue2_kernel(const float* __restrict__ oadj, const float* __restrict__ ssb,
                                                        const _Float16* __restrict__ outp16, const float* __restrict__ Wo,
                                                        const float* __restrict__ bo, const float* __restrict__ dn,
                                                        float* __restrict__ out) {
  __shared__ _Float16 outpS[64][136];
  __shared__ _Float16 WoT[128][136];
  __shared__ float red[256];
  __shared__ float rowsum[64];
  __shared__ float dw[4], w1[4], w2[4], w3[4];
  const int g = blockIdx.x, t = threadIdx.x;

  // stage Wo^T (fp32 [128k][128n] -> WoT[n][k] fp16)
#pragma unroll
  for (int i = 0; i < 16; i++) {
    int idx = i * 256 + t;
    int k = idx >> 5, n4 = (idx & 31) * 4;
    float4 w = *reinterpret_cast<const float4*>(Wo + k * 128 + n4);
    WoT[n4 + 0][k] = (_Float16)w.x;
    WoT[n4 + 1][k] = (_Float16)w.y;
    WoT[n4 + 2][k] = (_Float16)w.z;
    WoT[n4 + 3][k] = (_Float16)w.w;
  }
  // stage outp (fp16, 64x128) -> outpS
#pragma unroll
  for (int i = 0; i < 4; i++) {
    int idx = i * 256 + t;               // 1024 half8 slots
    int orow = idx >> 4, c8 = (idx & 15) * 8;
    half8v v = *reinterpret_cast<const half8v*>(&outp16[g * 8192 + orow * 128 + c8]);
    *reinterpret_cast<half8v*>(&outpS[orow][c8]) = v;
  }

  const int row = t >> 2, p = t & 3;
  float Areg[16];
  float trs_p = 0.f, ssq_p = 0.f;
#pragma unroll
  for (int c4 = 0; c4 < 4; c4++) {
    float4 a = *reinterpret_cast<const float4*>(&oadj[g * 4096 + row * 64 + p * 16 + c4 * 4]);
    Areg[c4 * 4 + 0] = a.x; Areg[c4 * 4 + 1] = a.y; Areg[c4 * 4 + 2] = a.z; Areg[c4 * 4 + 3] = a.w;
    float4 s = *reinterpret_cast<const float4*>(&ssb[g * 4096 + row * 64 + p * 16 + c4 * 4]);
    float vv[4] = {s.x, s.y, s.z, s.w};
#pragma unroll
    for (int jj = 0; jj < 4; jj++) {
      ssq_p += vv[jj] * vv[jj];
      int col = p * 16 + c4 * 4 + jj;
      if (col == row) trs_p += vv[jj];
    }
  }
  // mincut den
  float da = 0.f;
#pragma unroll
  for (int i = 0; i < 16; i++) da += dn[g * 4096 + i * 256 + t];
  float dws = wave_sum(da);
  if ((t & 63) == 0) dw[t >> 6] = dws;

  // row sums (off-diag) + traces
  float rs = 0.f, tra = 0.f;
#pragma unroll
  for (int c = 0; c < 16; c++) {
    int j = p * 16 + c;
    if (j == row) tra += Areg[c];
    else rs += Areg[c];
  }
  red[t] = rs;
  __syncthreads();
  if (p == 0) rowsum[row] = red[t] + red[t + 1] + red[t + 2] + red[t + 3];
  float v1 = wave_sum(tra), v2 = wave_sum(trs_p), v3 = wave_sum(ssq_p);
  if ((t & 63) == 0) { int w = t >> 6; w1[w] = v1; w2[w] = v2; w3[w] = v3; }
  __syncthreads();
  if (t == 0) {
    float TRA = w1[0] + w1[1] + w1[2] + w1[3];
    float TRS = w2[0] + w2[1] + w2[2] + w2[3];
    float SSQ = w3[0] + w3[1] + w3[2] + w3[3];
    float DEN = dw[0] + dw[1] + dw[2] + dw[3];
    atomicAdd(&out[98816], -(TRA / DEN) * 0.125f);
    float ssn = sqrtf(SSQ);
    atomicAdd(&out[98817], sqrtf(2.0f - TRS / (4.0f * ssn)) * 0.125f);
  }
  float di = sqrtf(rowsum[row]) + 1e-15f;
#pragma unroll
  for (int c = 0; c < 16; c++) {
    int j = p * 16 + c;
    float v = (j == row) ? 0.f : Areg[c];
    float dj = sqrtf(rowsum[j]) + 1e-15f;
    out[65536 + g * 4096 + row * 64 + j] = v / (di * dj);
  }
  if (t < 64) out[98304 + g * 64 + t] = (float)g;

  // pooled_x = relu(outp @ Wo + bo) via MFMA: M=64 (4 waves x 16 rows), N=128, K=128
  const int lane = t & 63;
  const int quad = lane >> 4, l16 = lane & 15;
  const int w = t >> 6;
  floatx4 acc[8];
#pragma unroll
  for (int ct = 0; ct < 8; ct++) acc[ct] = {0.f, 0.f, 0.f, 0.f};
#pragma unroll
  for (int kt = 0; kt < 4; kt++) {
    half8v af = *reinterpret_cast<const half8v*>(&outpS[w * 16 + l16][kt * 32 + quad * 8]);
#pragma unroll
    for (int ct = 0; ct < 8; ct++) {
      half8v bf = *reinterpret_cast<const half8v*>(&WoT[ct * 16 + l16][kt * 32 + quad * 8]);
      acc[ct] = __builtin_amdgcn_mfma_f32_16x16x32_f16(af, bf, acc[ct], 0, 0, 0);
    }
  }
#pragma unroll
  for (int r = 0; r < 4; r++) {
    int orow = w * 16 + quad * 4 + r;
#pragma unroll
    for (int ct = 0; ct < 8; ct++) {
      int col = ct * 16 + l16;
      float v = fmaxf(acc[ct][r] + bo[col], 0.f);
      out[(g * 64 + orow) * 128 + col] = v;
    }
  }
}

extern "C" void kernel_launch(void* const* d_in, const int* in_sizes, int n_in,
                              void* d_out, int out_size, void* d_ws, size_t ws_size,
                              hipStream_t stream) {
  const float* x   = (const float*)d_in[0];
  const int*   ei  = (const int*)d_in[1];
  const float* W1  = (const float*)d_in[3];
  const float* b1  = (const float*)d_in[4];
  const float* W2  = (const float*)d_in[5];
  const float* b2  = (const float*)d_in[6];
  const float* Wa1 = (const float*)d_in[7];
  const float* ba1 = (const float*)d_in[8];
  const float* Wa2 = (const float*)d_in[9];
  const float* ba2 = (const float*)d_in[10];
  const float* Wo  = (const float*)d_in[11];
  const float* bo  = (const float*)d_in[12];
  const int* src = ei;
  const int* dst = ei + NEDGES;
  float* out = (float*)d_out;

  char* ws = (char*)d_ws;
  size_t o = 0;
  auto alloc = [&](size_t bytes) -> void* {
    void* p = ws + o;
    o += (bytes + 255) & ~(size_t)255;
    return p;
  };
  _Float16* h16A = (_Float16*)alloc((size_t)NNODES * 128 * 2);  // 8 MB
  _Float16* h16B = (_Float16*)alloc((size_t)NNODES * 128 * 2);  // 8 MB
  _Float16* h16C = (_Float16*)alloc((size_t)NNODES * 128 * 2);  // 8 MB (h2, persists)
  _Float16* sh   = (_Float16*)alloc((size_t)NNODES * 64 * 2);   // 4 MB (s_d fp16)
  _Float16* Gh   = (_Float16*)alloc((size_t)NNODES * 64 * 2);   // 4 MB
  float* pF    = (float*)alloc((size_t)256 * 16384 * 4);        // 16 MB
  float* dis   = (float*)alloc((size_t)NNODES * 4);
  int* outdeg  = (int*)alloc((size_t)NNODES * 4);
  int* offs    = (int*)alloc((size_t)(NNODES + 1) * 4);
  int* ssrc    = (int*)alloc((size_t)NEDGES * 4);
  int* pIn     = (int*)alloc((size_t)8 * CPG * 4096 * 4);
  int* pOut    = (int*)alloc((size_t)8 * CPG * 4096 * 4);
  int* cbase   = (int*)alloc((size_t)8 * CPG * 4096 * 4);
  float* dn    = (float*)alloc((size_t)NNODES * 4);
  float* oadj  = (float*)alloc(8 * 4096 * 4);
  float* ssb   = (float*)alloc(8 * 4096 * 4);
  _Float16* outp16 = (_Float16*)alloc(8 * 8192 * 2);

  hipMemsetAsync(out + 98816, 0, 2 * sizeof(float), stream);

  hist2_kernel<<<8 * CPG, 256, 0, stream>>>(src, dst, pIn, pOut);
  scan2_kernel<<<8, 1024, 0, stream>>>(pIn, pOut, offs, cbase, outdeg, dis);
  scatter2_kernel<<<8 * CPG, 256, 0, stream>>>(src, dst, cbase, ssrc);

  // GCN layer 1: hs = dis .* (x @ W1) [fp32 in, fp16 out]; h1 = relu(...)
  mgemm_kernel<128, 0, 0, 1, 1, 1, 0><<<NNODES / 128, 256, 0, stream>>>(x, W1, nullptr, dis, nullptr, nullptr, h16A);
  aggregate_kernel<<<NNODES / 4, 256, 0, stream>>>(h16A, dis, offs, ssrc, b1, h16B, 1);
  // GCN layer 2: h2 [fp16]
  mgemm_kernel<128, 0, 0, 1, 0, 1, 0><<<NNODES / 128, 256, 0, stream>>>(h16B, W2, nullptr, dis, nullptr, nullptr, h16A);
  aggregate_kernel<<<NNODES / 4, 256, 0, stream>>>(h16A, dis, offs, ssrc, b2, h16C, 0);

  // assignment MLP: z = tanh(h2 @ Wa1 + ba1) [fp16]; s_d = dsoftmax(z @ Wa2 + ba2) [fp16, fused]
  mgemm_kernel<128, 2, 1, 0, 0, 1, 0><<<NNODES / 128, 256, 0, stream>>>(h16C, Wa1, ba1, nullptr, nullptr, nullptr, h16A);
  mgemm_kernel<64, 0, 1, 0, 0, 0, 1><<<NNODES / 128, 256, 0, stream>>>(h16A, Wa2, ba2, nullptr, outdeg, dn, sh);

  gather_kernel<<<NNODES / 4, 256, 0, stream>>>(sh, offs, ssrc, Gh);
  fused_atb_kernel<<<256, 512, 0, stream>>>(sh, Gh, h16C, pF);
  merge_kernel<<<128, 256, 0, stream>>>(pF, oadj, ssb, outp16);
  epilogue2_kernel<<<8, 256, 0, stream>>>(oadj, ssb, outp16, Wo, bo, dn, out);
}

// Round 10
// 216.211 us; speedup vs baseline: 1.8265x; 1.1157x over previous
//
#include <hip/hip_runtime.h>

#define NNODES 32768
#define NEDGES 524288
#define KCL 64
#define CPG 16   // histogram chunks per graph (4096 edges each)

typedef _Float16 half8v __attribute__((ext_vector_type(8)));
typedef _Float16 half4v __attribute__((ext_vector_type(4)));
typedef float floatx4 __attribute__((ext_vector_type(4)));

// fp16 transposed weight buffer layout (element offsets into wt16):
#define WT1_OFF   0       // W1  [128x128] -> [n*128+k]
#define WT2_OFF   16384   // W2  [128x128]
#define WTA1_OFF  32768   // Wa1 [128x128]
#define WTA2_OFF  49152   // Wa2 [128x64]  -> [n*128+k], n<64
#define WTO_OFF   57344   // Wo  [128x128]
#define WT_TOTAL  73728

__device__ __forceinline__ float wave_sum(float v) {
#pragma unroll
  for (int off = 32; off > 0; off >>= 1) v += __shfl_xor(v, off, 64);
  return v;
}

// ---------------- per-chunk LDS histogram (indeg only) + weight fp16-transpose prep ----------------
__global__ __launch_bounds__(256) void hist2_kernel(const int* __restrict__ src, const int* __restrict__ dst,
                                                    int* __restrict__ pIn,
                                                    const float* __restrict__ W1, const float* __restrict__ W2,
                                                    const float* __restrict__ Wa1, const float* __restrict__ Wa2,
                                                    const float* __restrict__ Wo, _Float16* __restrict__ wt16) {
  __shared__ int hIn[4096];
  const int t = threadIdx.x;
  const int g = blockIdx.x >> 4;
  const int ebase = (g << 16) + ((blockIdx.x & 15) << 12);
  const int nbase = g << 12;
  for (int i = t; i < 4096; i += 256) hIn[i] = 0;
  __syncthreads();
  // weight prep interleaved (independent of histogram)
  {
    int tg = blockIdx.x * 256 + t;
#pragma unroll
    for (int i = 0; i < 3; i++) {
      int id = tg + i * 32768;
      if (id < WT_TOTAL) {
        const float* W; int base, BN;
        if (id < 16384)      { W = W1;  base = WT1_OFF;  BN = 128; }
        else if (id < 32768) { W = W2;  base = WT2_OFF;  BN = 128; }
        else if (id < 49152) { W = Wa1; base = WTA1_OFF; BN = 128; }
        else if (id < 57344) { W = Wa2; base = WTA2_OFF; BN = 64; }
        else                 { W = Wo;  base = WTO_OFF;  BN = 128; }
        int m = id - base;
        int k = m / BN, n = m % BN;
        wt16[base + n * 128 + k] = (_Float16)W[m];
      }
    }
  }
#pragma unroll
  for (int i = 0; i < 16; ++i) {
    int e = ebase + i * 256 + t;
    atomicAdd(&hIn[dst[e] - nbase], 1);
  }
  __syncthreads();
  int* dIn = pIn + ((size_t)blockIdx.x << 12);
  for (int i = t; i < 4096; i += 256) dIn[i] = hIn[i];
}

// ---------------- per-graph scan: offs, dis, per-chunk cursor bases ----------------
__global__ __launch_bounds__(1024) void scan2_kernel(const int* __restrict__ pIn, int* __restrict__ offs,
                                                     int* __restrict__ cbase, float* __restrict__ dis) {
  __shared__ int part[1024];
  const int t = threadIdx.x;
  const int g = blockIdx.x;
  int tot[4];
  int s = 0;
#pragma unroll
  for (int j = 0; j < 4; ++j) {
    int l = t * 4 + j;
    int cnt = 0;
#pragma unroll
    for (int c = 0; c < CPG; ++c) cnt += pIn[(((size_t)(g * CPG + c)) << 12) + l];
    tot[j] = cnt;
    s += cnt;
  }
  part[t] = s;
  __syncthreads();
  for (int off = 1; off < 1024; off <<= 1) {
    int add = (t >= off) ? part[t - off] : 0;
    __syncthreads();
    part[t] += add;
    __syncthreads();
  }
  int run = (g << 16) + ((t == 0) ? 0 : part[t - 1]);
#pragma unroll
  for (int j = 0; j < 4; ++j) {
    int l = t * 4 + j;
    int n = (g << 12) + l;
    offs[n] = run;
    dis[n] = rsqrtf((float)tot[j] + 1.0f);
    int running = run;
#pragma unroll
    for (int c = 0; c < CPG; ++c) {
      size_t idx = (((size_t)(g * CPG + c)) << 12) + l;
      cbase[idx] = running;
      running += pIn[idx];
    }
    run += tot[j];
  }
  if (g == 0 && t == 0) offs[NNODES] = NEDGES;
}

// ---------------- scatter via LDS cursors (no global atomics) ----------------
__global__ __launch_bounds__(256) void scatter2_kernel(const int* __restrict__ src, const int* __restrict__ dst,
                                                       const int* __restrict__ cbase, int* __restrict__ ssrc) {
  __shared__ int cur[4096];
  const int t = threadIdx.x;
  const int g = blockIdx.x >> 4;
  const int ebase = (g << 16) + ((blockIdx.x & 15) << 12);
  const int nbase = g << 12;
  const int* cb = cbase + ((size_t)blockIdx.x << 12);
  for (int i = t; i < 4096; i += 256) cur[i] = cb[i];
  __syncthreads();
#pragma unroll
  for (int i = 0; i < 16; ++i) {
    int e = ebase + i * 256 + t;
    int d = dst[e] - nbase;
    int pos = atomicAdd(&cur[d], 1);
    ssrc[pos] = src[e];
  }
}

// ---------------- MFMA fp16 GEMM: C[M x 128] = A[M x 128] @ W, W pre-transposed fp16 ----------------
template <int ACT, int BIAS, int SCALE, int AFP32>
__global__ __launch_bounds__(256) void mgemm_kernel(const void* __restrict__ Ain, const _Float16* __restrict__ WT16,
                                                    const float* __restrict__ bias, const float* __restrict__ rowscale,
                                                    _Float16* __restrict__ Cout) {
  __shared__ _Float16 WT[128][136];
  const int t = threadIdx.x;
#pragma unroll
  for (int i = 0; i < 8; i++) {
    int idx = i * 256 + t;
    int n = idx >> 4, k8 = (idx & 15) << 3;
    *reinterpret_cast<half8v*>(&WT[n][k8]) = *reinterpret_cast<const half8v*>(&WT16[n * 128 + k8]);
  }
  __syncthreads();
  const int lane = t & 63;
  const int quad = lane >> 4, l16 = lane & 15;
  const long rowbase = (long)(blockIdx.x & 7) * 4096 + (long)(blockIdx.x >> 3) * 128 + (t >> 6) * 32;
  half8v af[2][4];
#pragma unroll
  for (int rt = 0; rt < 2; rt++)
#pragma unroll
    for (int kt = 0; kt < 4; kt++) {
      if (AFP32) {
        const float* A32 = (const float*)Ain;
        const float* p = A32 + (rowbase + rt * 16 + l16) * 128 + kt * 32 + quad * 8;
        float4 p0 = *reinterpret_cast<const float4*>(p);
        float4 p1 = *reinterpret_cast<const float4*>(p + 4);
        half8v h = {(_Float16)p0.x, (_Float16)p0.y, (_Float16)p0.z, (_Float16)p0.w,
                    (_Float16)p1.x, (_Float16)p1.y, (_Float16)p1.z, (_Float16)p1.w};
        af[rt][kt] = h;
      } else {
        const _Float16* A16 = (const _Float16*)Ain;
        af[rt][kt] = *reinterpret_cast<const half8v*>(A16 + (rowbase + rt * 16 + l16) * 128 + kt * 32 + quad * 8);
      }
    }
  floatx4 acc[2][8];
#pragma unroll
  for (int rt = 0; rt < 2; rt++)
#pragma unroll
    for (int ct = 0; ct < 8; ct++) acc[rt][ct] = {0.f, 0.f, 0.f, 0.f};
#pragma unroll
  for (int kt = 0; kt < 4; kt++) {
    half8v bf[8];
#pragma unroll
    for (int ct = 0; ct < 8; ct++)
      bf[ct] = *reinterpret_cast<const half8v*>(&WT[ct * 16 + l16][kt * 32 + quad * 8]);
#pragma unroll
    for (int rt = 0; rt < 2; rt++)
#pragma unroll
      for (int ct = 0; ct < 8; ct++)
        acc[rt][ct] = __builtin_amdgcn_mfma_f32_16x16x32_f16(af[rt][kt], bf[ct], acc[rt][ct], 0, 0, 0);
  }
#pragma unroll
  for (int rt = 0; rt < 2; rt++) {
#pragma unroll
    for (int r = 0; r < 4; r++) {
      long row = rowbase + rt * 16 + quad * 4 + r;
      float sc = SCALE ? rowscale[row] : 1.f;
#pragma unroll
      for (int ct = 0; ct < 8; ct++) {
        float v = acc[rt][ct][r];
        if (SCALE) v *= sc;
        if (BIAS) v += bias[ct * 16 + l16];
        if (ACT == 1) v = fmaxf(v, 0.f);
        Cout[row * 128 + ct * 16 + l16] = (_Float16)v;
      }
    }
  }
}

// ---------------- fused assignment MLP: z = tanh(h2@Wa1+ba1) in LDS; s_d = dsoftmax(z@Wa2+ba2) ----------------
__global__ __launch_bounds__(256) void mlp_kernel(const _Float16* __restrict__ h2, const _Float16* __restrict__ wta1,
                                                  const _Float16* __restrict__ wta2, const float* __restrict__ ba1,
                                                  const float* __restrict__ ba2, _Float16* __restrict__ sh) {
  __shared__ _Float16 WT1[128][136];
  __shared__ _Float16 WT2[64][136];
  __shared__ _Float16 Z[128][136];
  const int t = threadIdx.x;
#pragma unroll
  for (int i = 0; i < 8; i++) {
    int idx = i * 256 + t;
    int n = idx >> 4, k8 = (idx & 15) << 3;
    *reinterpret_cast<half8v*>(&WT1[n][k8]) = *reinterpret_cast<const half8v*>(&wta1[n * 128 + k8]);
  }
#pragma unroll
  for (int i = 0; i < 4; i++) {
    int idx = i * 256 + t;
    int n = idx >> 4, k8 = (idx & 15) << 3;
    *reinterpret_cast<half8v*>(&WT2[n][k8]) = *reinterpret_cast<const half8v*>(&wta2[n * 128 + k8]);
  }
  __syncthreads();
  const int lane = t & 63;
  const int quad = lane >> 4, l16 = lane & 15;
  const int w = t >> 6;
  const long rowbase = (long)(blockIdx.x & 7) * 4096 + (long)(blockIdx.x >> 3) * 128 + w * 32;
  half8v af[2][4];
#pragma unroll
  for (int rt = 0; rt < 2; rt++)
#pragma unroll
    for (int kt = 0; kt < 4; kt++)
      af[rt][kt] = *reinterpret_cast<const half8v*>(h2 + (rowbase + rt * 16 + l16) * 128 + kt * 32 + quad * 8);
  {
    floatx4 acc[2][8];
#pragma unroll
    for (int rt = 0; rt < 2; rt++)
#pragma unroll
      for (int ct = 0; ct < 8; ct++) acc[rt][ct] = {0.f, 0.f, 0.f, 0.f};
#pragma unroll
    for (int kt = 0; kt < 4; kt++) {
      half8v bf[8];
#pragma unroll
      for (int ct = 0; ct < 8; ct++)
        bf[ct] = *reinterpret_cast<const half8v*>(&WT1[ct * 16 + l16][kt * 32 + quad * 8]);
#pragma unroll
      for (int rt = 0; rt < 2; rt++)
#pragma unroll
        for (int ct = 0; ct < 8; ct++)
          acc[rt][ct] = __builtin_amdgcn_mfma_f32_16x16x32_f16(af[rt][kt], bf[ct], acc[rt][ct], 0, 0, 0);
    }
#pragma unroll
    for (int rt = 0; rt < 2; rt++)
#pragma unroll
      for (int r = 0; r < 4; r++) {
        int lrow = w * 32 + rt * 16 + quad * 4 + r;
#pragma unroll
        for (int ct = 0; ct < 8; ct++) {
          float v = tanhf(acc[rt][ct][r] + ba1[ct * 16 + l16]);
          Z[lrow][ct * 16 + l16] = (_Float16)v;
        }
      }
  }
  __syncthreads();
  // phase 2: logits = z @ Wa2 + ba2 -> double softmax -> sh
  half8v af2[2][4];
#pragma unroll
  for (int rt = 0; rt < 2; rt++)
#pragma unroll
    for (int kt = 0; kt < 4; kt++)
      af2[rt][kt] = *reinterpret_cast<const half8v*>(&Z[w * 32 + rt * 16 + l16][kt * 32 + quad * 8]);
  floatx4 acc2[2][4];
#pragma unroll
  for (int rt = 0; rt < 2; rt++)
#pragma unroll
    for (int ct = 0; ct < 4; ct++) acc2[rt][ct] = {0.f, 0.f, 0.f, 0.f};
#pragma unroll
  for (int kt = 0; kt < 4; kt++) {
    half8v bf[4];
#pragma unroll
    for (int ct = 0; ct < 4; ct++)
      bf[ct] = *reinterpret_cast<const half8v*>(&WT2[ct * 16 + l16][kt * 32 + quad * 8]);
#pragma unroll
    for (int rt = 0; rt < 2; rt++)
#pragma unroll
      for (int ct = 0; ct < 4; ct++)
        acc2[rt][ct] = __builtin_amdgcn_mfma_f32_16x16x32_f16(af2[rt][kt], bf[ct], acc2[rt][ct], 0, 0, 0);
  }
#pragma unroll
  for (int rt = 0; rt < 2; rt++) {
#pragma unroll
    for (int r = 0; r < 4; r++) {
      long row = rowbase + rt * 16 + quad * 4 + r;
      float v[4];
#pragma unroll
      for (int ct = 0; ct < 4; ct++) v[ct] = acc2[rt][ct][r] + ba2[ct * 16 + l16];
      float m = fmaxf(fmaxf(v[0], v[1]), fmaxf(v[2], v[3]));
#pragma unroll
      for (int off = 1; off <= 8; off <<= 1) m = fmaxf(m, __shfl_xor(m, off, 64));
      float se = 0.f;
#pragma unroll
      for (int ct = 0; ct < 4; ct++) { v[ct] = __expf(v[ct] - m); se += v[ct]; }
#pragma unroll
      for (int off = 1; off <= 8; off <<= 1) se += __shfl_xor(se, off, 64);
      float inv = 1.0f / se;
#pragma unroll
      for (int ct = 0; ct < 4; ct++) v[ct] *= inv;
      float m2 = fmaxf(fmaxf(v[0], v[1]), fmaxf(v[2], v[3]));
#pragma unroll
      for (int off = 1; off <= 8; off <<= 1) m2 = fmaxf(m2, __shfl_xor(m2, off, 64));
      float se2 = 0.f;
#pragma unroll
      for (int ct = 0; ct < 4; ct++) { v[ct] = __expf(v[ct] - m2); se2 += v[ct]; }
#pragma unroll
      for (int off = 1; off <= 8; off <<= 1) se2 += __shfl_xor(se2, off, 64);
      float inv2 = 1.0f / se2;
#pragma unroll
      for (int ct = 0; ct < 4; ct++) sh[row * 64 + ct * 16 + l16] = (_Float16)(v[ct] * inv2);
    }
  }
}

// ---------------- GCN aggregation over fp16 pre-scaled hs (XCD-swizzled, parallel tail) ----------------
__global__ __launch_bounds__(256) void aggregate_kernel(const _Float16* __restrict__ hs, const float* __restrict__ dis,
                                                        const int* __restrict__ offs, const int* __restrict__ ssrc,
                                                        const float* __restrict__ bias, _Float16* __restrict__ outh,
                                                        int relu) {
  const int lane = threadIdx.x & 63;
  const int b = blockIdx.x;
  const int node = ((b & 7) << 12) + ((b >> 3) << 2) + (threadIdx.x >> 6);
  const int q = lane >> 4;
  const int fl = (lane & 15) * 8;
  const int e0 = offs[node], e1 = offs[node + 1];
  float fa[8];
#pragma unroll
  for (int j = 0; j < 8; j++) fa[j] = 0.f;
  int e = e0;
  for (; e + 16 <= e1; e += 16) {
    int s0 = ssrc[e + q];
    int s1 = ssrc[e + 4 + q];
    int s2 = ssrc[e + 8 + q];
    int s3 = ssrc[e + 12 + q];
    half8v v0 = *reinterpret_cast<const half8v*>(hs + (size_t)s0 * 128 + fl);
    half8v v1 = *reinterpret_cast<const half8v*>(hs + (size_t)s1 * 128 + fl);
    half8v v2 = *reinterpret_cast<const half8v*>(hs + (size_t)s2 * 128 + fl);
    half8v v3 = *reinterpret_cast<const half8v*>(hs + (size_t)s3 * 128 + fl);
#pragma unroll
    for (int j = 0; j < 8; j++) fa[j] += (float)v0[j] + (float)v1[j] + (float)v2[j] + (float)v3[j];
  }
  if (e < e1) {  // parallel masked tail
    int last = e1 - 1;
    int i0 = e + q, i1 = e + 4 + q, i2 = e + 8 + q, i3 = e + 12 + q;
    bool m0 = i0 < e1, m1 = i1 < e1, m2 = i2 < e1, m3 = i3 < e1;
    int s0 = ssrc[i0 < last ? i0 : last];
    int s1 = ssrc[i1 < last ? i1 : last];
    int s2 = ssrc[i2 < last ? i2 : last];
    int s3 = ssrc[i3 < last ? i3 : last];
    half8v v0 = *reinterpret_cast<const half8v*>(hs + (size_t)s0 * 128 + fl);
    half8v v1 = *reinterpret_cast<const half8v*>(hs + (size_t)s1 * 128 + fl);
    half8v v2 = *reinterpret_cast<const half8v*>(hs + (size_t)s2 * 128 + fl);
    half8v v3 = *reinterpret_cast<const half8v*>(hs + (size_t)s3 * 128 + fl);
#pragma unroll
    for (int j = 0; j < 8; j++) {
      fa[j] += (m0 ? (float)v0[j] : 0.f) + (m1 ? (float)v1[j] : 0.f) +
               (m2 ? (float)v2[j] : 0.f) + (m3 ? (float)v3[j] : 0.f);
    }
  }
#pragma unroll
  for (int j = 0; j < 8; j++) {
    fa[j] += __shfl_xor(fa[j], 16, 64);
    fa[j] += __shfl_xor(fa[j], 32, 64);
  }
  if (q == 0) {
    float dn = dis[node];
    half8v self = *reinterpret_cast<const half8v*>(hs + (size_t)node * 128 + fl);
    float4 b0 = *reinterpret_cast<const float4*>(bias + fl);
    float4 b1 = *reinterpret_cast<const float4*>(bias + fl + 4);
    float bb[8] = {b0.x, b0.y, b0.z, b0.w, b1.x, b1.y, b1.z, b1.w};
    half8v r;
#pragma unroll
    for (int j = 0; j < 8; j++) {
      float v = fmaf(fa[j] + (float)self[j], dn, bb[j]);
      if (relu) v = fmaxf(v, 0.f);
      r[j] = (_Float16)v;
    }
    *reinterpret_cast<half8v*>(outh + (size_t)node * 128 + fl) = r;
  }
}

// ---------------- G[m] = sum_{src->m} s_d[src] + per-node den partial ----------------
__global__ __launch_bounds__(256) void gather_kernel(const _Float16* __restrict__ sh, const int* __restrict__ offs,
                                                     const int* __restrict__ ssrc, _Float16* __restrict__ Gh,
                                                     float* __restrict__ dnp) {
  const int lane = threadIdx.x & 63;
  const int b = blockIdx.x;
  const int node = ((b & 7) << 12) + ((b >> 3) << 2) + (threadIdx.x >> 6);
  const int q = lane >> 3;          // 0..7 edge slot
  const int fl = (lane & 7) * 8;    // 8 lanes x 8 halves = 64
  const int e0 = offs[node], e1 = offs[node + 1];
  float fa[8];
  float sq = 0.f;
#pragma unroll
  for (int j = 0; j < 8; j++) fa[j] = 0.f;
  int e = e0;
  for (; e + 16 <= e1; e += 16) {
    int s0 = ssrc[e + q];
    int s1 = ssrc[e + 8 + q];
    half8v v0 = *reinterpret_cast<const half8v*>(sh + (size_t)s0 * 64 + fl);
    half8v v1 = *reinterpret_cast<const half8v*>(sh + (size_t)s1 * 64 + fl);
#pragma unroll
    for (int j = 0; j < 8; j++) {
      float f0 = (float)v0[j], f1 = (float)v1[j];
      fa[j] += f0 + f1;
      sq = fmaf(f0, f0, sq);
      sq = fmaf(f1, f1, sq);
    }
  }
  if (e < e1) {
    int last = e1 - 1;
    int i0 = e + q, i1 = e + 8 + q;
    bool m0 = i0 < e1, m1 = i1 < e1;
    int s0 = ssrc[i0 < last ? i0 : last];
    int s1 = ssrc[i1 < last ? i1 : last];
    half8v v0 = *reinterpret_cast<const half8v*>(sh + (size_t)s0 * 64 + fl);
    half8v v1 = *reinterpret_cast<const half8v*>(sh + (size_t)s1 * 64 + fl);
#pragma unroll
    for (int j = 0; j < 8; j++) {
      float f0 = m0 ? (float)v0[j] : 0.f;
      float f1 = m1 ? (float)v1[j] : 0.f;
      fa[j] += f0 + f1;
      sq = fmaf(f0, f0, sq);
      sq = fmaf(f1, f1, sq);
    }
  }
#pragma unroll
  for (int j = 0; j < 8; j++) {
    fa[j] += __shfl_xor(fa[j], 8, 64);
    fa[j] += __shfl_xor(fa[j], 16, 64);
    fa[j] += __shfl_xor(fa[j], 32, 64);
  }
  float den = wave_sum(sq);
  if (lane == 0) dnp[node] = den;
  if (q == 0) {
    half8v r;
#pragma unroll
    for (int j = 0; j < 8; j++) r[j] = (_Float16)fa[j];
    *reinterpret_cast<half8v*>(Gh + (size_t)node * 64 + fl) = r;
  }
}

// ---------------- fused rank reduction: C[64 x 256] = s_chunk^T [G | s | h2] ----------------
__global__ __launch_bounds__(512) void fused_atb_kernel(const _Float16* __restrict__ sh, const _Float16* __restrict__ Gh,
                                                        const _Float16* __restrict__ h2, float* __restrict__ pF) {
  __shared__ float Xs[32][64];
  __shared__ float Ys[32][256];
  const int t = threadIdx.x;
  const int g = blockIdx.x & 7, chunk = blockIdx.x >> 3;
  const int n0 = g * 4096 + chunk * 128;
  const int rg = t >> 6;
  const int cl = t & 63;
  float acc[8][4];
#pragma unroll
  for (int r = 0; r < 8; r++)
#pragma unroll
    for (int j = 0; j < 4; j++) acc[r][j] = 0.f;

  for (int kt = 0; kt < 4; ++kt) {
    const int nb = n0 + kt * 32;
    {
      int k = t >> 4, c = (t & 15) * 4;
      half4v hv = *reinterpret_cast<const half4v*>(&sh[(size_t)(nb + k) * 64 + c]);
      float4 val = {(float)hv[0], (float)hv[1], (float)hv[2], (float)hv[3]};
      *reinterpret_cast<float4*>(&Xs[k][c]) = val;
    }
#pragma unroll
    for (int it = 0; it < 4; ++it) {
      int slot = it * 512 + t;
      int k = slot >> 6, c = (slot & 63) * 4;
      half4v hv;
      if (c < 64)       hv = *reinterpret_cast<const half4v*>(&Gh[(size_t)(nb + k) * 64 + c]);
      else if (c < 128) hv = *reinterpret_cast<const half4v*>(&sh[(size_t)(nb + k) * 64 + (c - 64)]);
      else              hv = *reinterpret_cast<const half4v*>(&h2[(size_t)(nb + k) * 128 + (c - 128)]);
      float4 val = {(float)hv[0], (float)hv[1], (float)hv[2], (float)hv[3]};
      *reinterpret_cast<float4*>(&Ys[k][c]) = val;
    }
    __syncthreads();
#pragma unroll
    for (int k = 0; k < 32; ++k) {
      float4 b4 = *reinterpret_cast<const float4*>(&Ys[k][cl * 4]);
      float4 a0 = *reinterpret_cast<const float4*>(&Xs[k][rg * 8]);
      float4 a1 = *reinterpret_cast<const float4*>(&Xs[k][rg * 8 + 4]);
      float a[8] = {a0.x, a0.y, a0.z, a0.w, a1.x, a1.y, a1.z, a1.w};
#pragma unroll
      for (int r = 0; r < 8; r++) {
        acc[r][0] = fmaf(a[r], b4.x, acc[r][0]);
        acc[r][1] = fmaf(a[r], b4.y, acc[r][1]);
        acc[r][2] = fmaf(a[r], b4.z, acc[r][2]);
        acc[r][3] = fmaf(a[r], b4.w, acc[r][3]);
      }
    }
    __syncthreads();
  }
  float* dst = pF + (size_t)blockIdx.x * 16384;
#pragma unroll
  for (int r = 0; r < 8; r++) {
    float4 o4 = {acc[r][0], acc[r][1], acc[r][2], acc[r][3]};
    *reinterpret_cast<float4*>(&dst[(rg * 8 + r) * 256 + cl * 4]) = o4;
  }
}

// ---------------- merge 32 partials/graph -> oadj (fp32), ssb (fp32), outp (fp16) ----------------
__global__ __launch_bounds__(256) void merge_kernel(const float* __restrict__ pF, float* __restrict__ oadj,
                                                    float* __restrict__ ssb, _Float16* __restrict__ outp16) {
  int idx = blockIdx.x * 256 + threadIdx.x;
  int g = idx >> 12, o4 = idx & 4095;
  float sx = 0.f, sy = 0.f, sz = 0.f, sw = 0.f;
#pragma unroll
  for (int q = 0; q < 32; ++q) {
    float4 v = *reinterpret_cast<const float4*>(pF + (size_t)(q * 8 + g) * 16384 + o4 * 4);
    sx += v.x; sy += v.y; sz += v.z; sw += v.w;
  }
  int row = o4 >> 6;
  int c = (o4 & 63) * 4;
  if (c < 64) {
    float4 o = {sx, sy, sz, sw};
    *reinterpret_cast<float4*>(&oadj[g * 4096 + row * 64 + c]) = o;
  } else if (c < 128) {
    float4 o = {sx, sy, sz, sw};
    *reinterpret_cast<float4*>(&ssb[g * 4096 + row * 64 + (c - 64)]) = o;
  } else {
    half4v h = {(_Float16)sx, (_Float16)sy, (_Float16)sz, (_Float16)sw};
    *reinterpret_cast<half4v*>(&outp16[g * 8192 + row * 128 + (c - 128)]) = h;
  }
}

// ---------------- epilogue2: losses + adj-norm + pooled MFMA GEMM (8 blocks) ----------------
__global__ __launch_bounds__(256) void epilogue2_kernel(const float* __restrict__ oadj, const float* __restrict__ ssb,
                                                        const _Float16* __restrict__ outp16, const _Float16* __restrict__ wto,
                                                        const float* __restrict__ bo, const float* __restrict__ dn,
                                                        float* __restrict__ out) {
  __shared__ _Float16 outpS[64][136];
  __shared__ _Float16 WoT[128][136];
  __shared__ float red[256];
  __shared__ float rowsum[64];
  __shared__ float dw[4], w1[4], w2[4], w3[4];
  const int g = blockIdx.x, t = threadIdx.x;

#pragma unroll
  for (int i = 0; i < 8; i++) {
    int idx = i * 256 + t;
    int n = idx >> 4, k8 = (idx & 15) << 3;
    *reinterpret_cast<half8v*>(&WoT[n][k8]) = *reinterpret_cast<const half8v*>(&wto[n * 128 + k8]);
  }
#pragma unroll
  for (int i = 0; i < 4; i++) {
    int idx = i * 256 + t;
    int orow = idx >> 4, c8 = (idx & 15) * 8;
    half8v v = *reinterpret_cast<const half8v*>(&outp16[g * 8192 + orow * 128 + c8]);
    *reinterpret_cast<half8v*>(&outpS[orow][c8]) = v;
  }

  const int row = t >> 2, p = t & 3;
  float Areg[16];
  float trs_p = 0.f, ssq_p = 0.f;
#pragma unroll
  for (int c4 = 0; c4 < 4; c4++) {
    float4 a = *reinterpret_cast<const float4*>(&oadj[g * 4096 + row * 64 + p * 16 + c4 * 4]);
    Areg[c4 * 4 + 0] = a.x; Areg[c4 * 4 + 1] = a.y; Areg[c4 * 4 + 2] = a.z; Areg[c4 * 4 + 3] = a.w;
    float4 s = *reinterpret_cast<const float4*>(&ssb[g * 4096 + row * 64 + p * 16 + c4 * 4]);
    float vv[4] = {s.x, s.y, s.z, s.w};
#pragma unroll
    for (int jj = 0; jj < 4; jj++) {
      ssq_p += vv[jj] * vv[jj];
      int col = p * 16 + c4 * 4 + jj;
      if (col == row) trs_p += vv[jj];
    }
  }
  float da = 0.f;
#pragma unroll
  for (int i = 0; i < 16; i++) da += dn[g * 4096 + i * 256 + t];
  float dws = wave_sum(da);
  if ((t & 63) == 0) dw[t >> 6] = dws;

  float rs = 0.f, tra = 0.f;
#pragma unroll
  for (int c = 0; c < 16; c++) {
    int j = p * 16 + c;
    if (j == row) tra += Areg[c];
    else rs += Areg[c];
  }
  red[t] = rs;
  __syncthreads();
  if (p == 0) rowsum[row] = red[t] + red[t + 1] + red[t + 2] + red[t + 3];
  float v1 = wave_sum(tra), v2 = wave_sum(trs_p), v3 = wave_sum(ssq_p);
  if ((t & 63) == 0) { int w = t >> 6; w1[w] = v1; w2[w] = v2; w3[w] = v3; }
  __syncthreads();
  if (t == 0) {
    float TRA = w1[0] + w1[1] + w1[2] + w1[3];
    float TRS = w2[0] + w2[1] + w2[2] + w2[3];
    float SSQ = w3[0] + w3[1] + w3[2] + w3[3];
    float DEN = dw[0] + dw[1] + dw[2] + dw[3];
    atomicAdd(&out[98816], -(TRA / DEN) * 0.125f);
    float ssn = sqrtf(SSQ);
    atomicAdd(&out[98817], sqrtf(2.0f - TRS / (4.0f * ssn)) * 0.125f);
  }
  float di = sqrtf(rowsum[row]) + 1e-15f;
#pragma unroll
  for (int c = 0; c < 16; c++) {
    int j = p * 16 + c;
    float v = (j == row) ? 0.f : Areg[c];
    float dj = sqrtf(rowsum[j]) + 1e-15f;
    out[65536 + g * 4096 + row * 64 + j] = v / (di * dj);
  }
  if (t < 64) out[98304 + g * 64 + t] = (float)g;

  const int lane = t & 63;
  const int quad = lane >> 4, l16 = lane & 15;
  const int w = t >> 6;
  floatx4 acc[8];
#pragma unroll
  for (int ct = 0; ct < 8; ct++) acc[ct] = {0.f, 0.f, 0.f, 0.f};
#pragma unroll
  for (int kt = 0; kt < 4; kt++) {
    half8v af = *reinterpret_cast<const half8v*>(&outpS[w * 16 + l16][kt * 32 + quad * 8]);
#pragma unroll
    for (int ct = 0; ct < 8; ct++) {
      half8v bf = *reinterpret_cast<const half8v*>(&WoT[ct * 16 + l16][kt * 32 + quad * 8]);
      acc[ct] = __builtin_amdgcn_mfma_f32_16x16x32_f16(af, bf, acc[ct], 0, 0, 0);
    }
  }
#pragma unroll
  for (int r = 0; r < 4; r++) {
    int orow = w * 16 + quad * 4 + r;
#pragma unroll
    for (int ct = 0; ct < 8; ct++) {
      int col = ct * 16 + l16;
      float v = fmaxf(acc[ct][r] + bo[col], 0.f);
      out[(g * 64 + orow) * 128 + col] = v;
    }
  }
}

extern "C" void kernel_launch(void* const* d_in, const int* in_sizes, int n_in,
                              void* d_out, int out_size, void* d_ws, size_t ws_size,
                              hipStream_t stream) {
  const float* x   = (const float*)d_in[0];
  const int*   ei  = (const int*)d_in[1];
  const float* W1  = (const float*)d_in[3];
  const float* b1  = (const float*)d_in[4];
  const float* W2  = (const float*)d_in[5];
  const float* b2  = (const float*)d_in[6];
  const float* Wa1 = (const float*)d_in[7];
  const float* ba1 = (const float*)d_in[8];
  const float* Wa2 = (const float*)d_in[9];
  const float* ba2 = (const float*)d_in[10];
  const float* Wo  = (const float*)d_in[11];
  const float* bo  = (const float*)d_in[12];
  const int* src = ei;
  const int* dst = ei + NEDGES;
  float* out = (float*)d_out;

  char* ws = (char*)d_ws;
  size_t o = 0;
  auto alloc = [&](size_t bytes) -> void* {
    void* p = ws + o;
    o += (bytes + 255) & ~(size_t)255;
    return p;
  };
  _Float16* h16A = (_Float16*)alloc((size_t)NNODES * 128 * 2);  // 8 MB
  _Float16* h16B = (_Float16*)alloc((size_t)NNODES * 128 * 2);  // 8 MB
  _Float16* h16C = (_Float16*)alloc((size_t)NNODES * 128 * 2);  // 8 MB (h2)
  _Float16* sh   = (_Float16*)alloc((size_t)NNODES * 64 * 2);   // 4 MB
  _Float16* Gh   = (_Float16*)alloc((size_t)NNODES * 64 * 2);   // 4 MB
  float* pF    = (float*)alloc((size_t)256 * 16384 * 4);        // 16 MB
  float* dis   = (float*)alloc((size_t)NNODES * 4);
  int* offs    = (int*)alloc((size_t)(NNODES + 1) * 4);
  int* ssrc    = (int*)alloc((size_t)NEDGES * 4);
  int* pIn     = (int*)alloc((size_t)8 * CPG * 4096 * 4);
  int* cbase   = (int*)alloc((size_t)8 * CPG * 4096 * 4);
  float* dn    = (float*)alloc((size_t)NNODES * 4);
  float* oadj  = (float*)alloc(8 * 4096 * 4);
  float* ssb   = (float*)alloc(8 * 4096 * 4);
  _Float16* outp16 = (_Float16*)alloc(8 * 8192 * 2);
  _Float16* wt16   = (_Float16*)alloc((size_t)WT_TOTAL * 2);

  hipMemsetAsync(out + 98816, 0, 2 * sizeof(float), stream);

  hist2_kernel<<<8 * CPG, 256, 0, stream>>>(src, dst, pIn, W1, W2, Wa1, Wa2, Wo, wt16);
  scan2_kernel<<<8, 1024, 0, stream>>>(pIn, offs, cbase, dis);
  scatter2_kernel<<<8 * CPG, 256, 0, stream>>>(src, dst, cbase, ssrc);

  // GCN layer 1: hs = dis .* (x @ W1); h1 = relu(...)
  mgemm_kernel<0, 0, 1, 1><<<NNODES / 128, 256, 0, stream>>>(x, wt16 + WT1_OFF, nullptr, dis, h16A);
  aggregate_kernel<<<NNODES / 4, 256, 0, stream>>>(h16A, dis, offs, ssrc, b1, h16B, 1);
  // GCN layer 2: h2
  mgemm_kernel<0, 0, 1, 0><<<NNODES / 128, 256, 0, stream>>>(h16B, wt16 + WT2_OFF, nullptr, dis, h16A);
  aggregate_kernel<<<NNODES / 4, 256, 0, stream>>>(h16A, dis, offs, ssrc, b2, h16C, 0);

  // fused assignment MLP + double softmax
  mlp_kernel<<<NNODES / 128, 256, 0, stream>>>(h16C, wt16 + WTA1_OFF, wt16 + WTA2_OFF, ba1, ba2, sh);

  gather_kernel<<<NNODES / 4, 256, 0, stream>>>(sh, offs, ssrc, Gh, dn);
  fused_atb_kernel<<<256, 512, 0, stream>>>(sh, Gh, h16C, pF);
  merge_kernel<<<128, 256, 0, stream>>>(pF, oadj, ssb, outp16);
  epilogue2_kernel<<<8, 256, 0, stream>>>(oadj, ssb, outp16, wt16 + WTO_OFF, bo, dn, out);
}